// Round 2
// baseline (489.545 us; speedup 1.0000x reference)
//
#include <hip/hip_runtime.h>

// Problem constants (match reference)
#define Bdim 4
#define Cdim 32
#define Hdim 512
#define Wdim 512
#define HWdim (Hdim * Wdim)

typedef __attribute__((ext_vector_type(4))) float    f32x4;
typedef __attribute__((ext_vector_type(2))) _Float16 f16x2;
typedef __attribute__((ext_vector_type(4))) _Float16 f16x4;
typedef __attribute__((ext_vector_type(8))) _Float16 f16x8;

// ---------------------------------------------------------------------------
// Kernel A: transpose x [B][C][H][W] (fp32) -> ws NHWC [B][H][W][C] (fp16)
// One block: (b, h) fixed, 128-wide w strip, all 32 c.
// float4 global loads, f32x4 LDS stores (pad 132 -> 16B-aligned, conflict-free),
// f16x8 (16B) NHWC stores, 2 per thread (32B contiguous each).
// ---------------------------------------------------------------------------
__global__ __launch_bounds__(256) void transpose_nhwc_half_kernel(
    const float* __restrict__ x, _Float16* __restrict__ ws)
{
    __shared__ float lds[Cdim * 132];   // 32 x 132 floats = 16896 B

    const int idx = blockIdx.x;               // B*H*4 = 8192 blocks
    const int tw  = idx & 3;                  // W/128 = 4 strips
    const int h   = (idx >> 2) & (Hdim - 1);
    const int b   = idx >> 11;
    const int w0  = tw * 128;
    const int t   = threadIdx.x;

    // 32c x 128w = 1024 float4s, 4 per thread. Issue all loads first (MLP).
    f32x4 r[4];
    #pragma unroll
    for (int i = 0; i < 4; ++i) {
        const int f4 = i * 256 + t;           // 0..1023
        const int c  = f4 >> 5;               // 32 float4 per row
        const int w4 = f4 & 31;
        r[i] = *(const f32x4*)(x + (((size_t)b * Cdim + c) * Hdim + h) * Wdim + w0 + w4 * 4);
    }
    #pragma unroll
    for (int i = 0; i < 4; ++i) {
        const int f4 = i * 256 + t;
        *(f32x4*)(lds + (f4 >> 5) * 132 + (f4 & 31) * 4) = r[i];
    }
    __syncthreads();

    // output block = 4096 halves contiguous; thread t writes halves [t*16, t*16+16)
    const size_t base = (((size_t)b * Hdim + h) * Wdim + w0) * Cdim;
    const int w_ = t >> 1;                    // local w (0..127)
    const int c0 = (t & 1) * 16;              // first channel (0 or 16)
    f16x8 v0, v1;
    #pragma unroll
    for (int k = 0; k < 8; ++k) v0[k] = (_Float16)lds[(c0 + k) * 132 + w_];
    #pragma unroll
    for (int k = 0; k < 8; ++k) v1[k] = (_Float16)lds[(c0 + 8 + k) * 132 + w_];
    *(f16x8*)(ws + base + (size_t)w_ * Cdim + c0)     = v0;   // 16B store
    *(f16x8*)(ws + base + (size_t)w_ * Cdim + c0 + 8) = v1;   // 16B store
}

// ---------------------------------------------------------------------------
// Kernel B: gather from NHWC fp16 ws + residual -> out (NCHW fp32)
// Block = 256 consecutive pixels of one row (b, h, w0..w0+255).
// Phase 1: per-pixel flow math -> LDS (NHWC half offsets, fp32 weights). 8 KB.
// Phase 2: 8 lanes per pixel, 4 channels each (f16x4 = 8B per corner load;
//          8 lanes x 8B = one full 64B NHWC line per corner). Accumulate fp32,
//          add residual loaded inline (nontemporal), store DIRECT to NCHW out:
//          per store instruction a wave writes 8 channels x 8 consecutive
//          pixels x 4B = 8 fully-used 32B runs -> write-combines in L2.
// No s_buf, no second barrier, no fp16 re-round of the result.
// ---------------------------------------------------------------------------
__global__ __launch_bounds__(256) void gather_nhwc_half_kernel(
    const _Float16* __restrict__ ws,
    const float* __restrict__ flow,
    const float* __restrict__ residual,
    float* __restrict__ out)
{
    __shared__ int   s_off[4][256];
    __shared__ float s_wt[4][256];

    const int idx = blockIdx.x;                 // 4096 blocks
    const int b   = idx >> 10;
    const int h   = (idx >> 1) & (Hdim - 1);
    const int w0  = (idx & 1) << 8;
    const int t   = threadIdx.x;

    // ---- Phase 1: per-pixel sampling math (numerics identical to prior) ----
    {
        const int w = w0 + t;
        const int pixg = h * Wdim + w;
        const float fx = flow[((size_t)b * 2 + 0) * HWdim + pixg];
        const float fy = flow[((size_t)b * 2 + 1) * HWdim + pixg];

        float gx = ((float)w + 0.5f) * (2.0f / (float)Wdim) - 1.0f + fx;
        float gy = ((float)h + 0.5f) * (2.0f / (float)Hdim) - 1.0f + fy;

        float tm = fmodf(gx + 1.0f, 2.0f);
        if (tm < 0.0f) tm += 2.0f;
        gx = tm - 1.0f;

        const float real_x = (gx + 1.0f) * ((float)Wdim * 0.5f) - 0.5f;
        const float real_y = (gy + 1.0f) * ((float)Hdim * 0.5f) - 0.5f;

        const float x0f = floorf(real_x);
        const float y0f = floorf(real_y);
        const float dx = real_x - x0f;
        const float dy = real_y - y0f;

        const int ix0 = (int)x0f;
        const int iy0 = (int)y0f;
        const int ix1 = ix0 + 1;
        const int iy1 = iy0 + 1;

        const bool vx0 = (ix0 >= 0) && (ix0 < Wdim);
        const bool vx1 = (ix1 >= 0) && (ix1 < Wdim);
        const bool vy0 = (iy0 >= 0) && (iy0 < Hdim);
        const bool vy1 = (iy1 >= 0) && (iy1 < Hdim);

        const int cx0 = min(max(ix0, 0), Wdim - 1);
        const int cx1 = min(max(ix1, 0), Wdim - 1);
        const int cy0 = min(max(iy0, 0), Hdim - 1);
        const int cy1 = min(max(iy1, 0), Hdim - 1);

        float w_tl = (1.0f - dx) * (1.0f - dy);
        float w_tr = dx * (1.0f - dy);
        float w_bl = (1.0f - dx) * dy;
        float w_br = dx * dy;
        if (!(vx0 && vy0)) w_tl = 0.0f;
        if (!(vx1 && vy0)) w_tr = 0.0f;
        if (!(vx0 && vy1)) w_bl = 0.0f;
        if (!(vx1 && vy1)) w_br = 0.0f;

        s_off[0][t] = (cy0 * Wdim + cx0) * Cdim;   // offsets in halves
        s_off[1][t] = (cy0 * Wdim + cx1) * Cdim;
        s_off[2][t] = (cy1 * Wdim + cx0) * Cdim;
        s_off[3][t] = (cy1 * Wdim + cx1) * Cdim;
        s_wt[0][t] = w_tl;
        s_wt[1][t] = w_tr;
        s_wt[2][t] = w_bl;
        s_wt[3][t] = w_br;
    }
    __syncthreads();

    // ---- Phase 2: coalesced channel-major gather, direct store ----
    {
        const int ci = t & 7;          // channel quad: channels 4ci..4ci+3
        const int c0 = ci * 4;
        const int p  = t >> 3;         // 0..31 pixel slot
        const _Float16* xb = ws + (size_t)b * (size_t)HWdim * Cdim + c0;
        // out/residual base for (b, c0, h, w0): channel stride = HWdim floats
        const size_t gbase = ((size_t)b * Cdim + c0) * (size_t)HWdim
                           + (size_t)h * Wdim + w0;

        #pragma unroll 4
        for (int j = 0; j < 8; ++j) {
            const int pix = j * 32 + p;
            const int o0 = s_off[0][pix];
            const int o1 = s_off[1][pix];
            const int o2 = s_off[2][pix];
            const int o3 = s_off[3][pix];
            const float w0_ = s_wt[0][pix];
            const float w1_ = s_wt[1][pix];
            const float w2_ = s_wt[2][pix];
            const float w3_ = s_wt[3][pix];

            const f16x4 v0 = *(const f16x4*)(xb + o0);   // 8B load, 8 lanes = 64B line
            const f16x4 v1 = *(const f16x4*)(xb + o1);
            const f16x4 v2 = *(const f16x4*)(xb + o2);
            const f16x4 v3 = *(const f16x4*)(xb + o3);

            const size_t gi = gbase + (size_t)pix;
            const float r0 = __builtin_nontemporal_load(residual + gi);
            const float r1 = __builtin_nontemporal_load(residual + gi + (size_t)HWdim);
            const float r2 = __builtin_nontemporal_load(residual + gi + (size_t)(2 * HWdim));
            const float r3 = __builtin_nontemporal_load(residual + gi + (size_t)(3 * HWdim));

            const float a0 = w0_ * (float)v0[0] + w1_ * (float)v1[0] + w2_ * (float)v2[0] + w3_ * (float)v3[0];
            const float a1 = w0_ * (float)v0[1] + w1_ * (float)v1[1] + w2_ * (float)v2[1] + w3_ * (float)v3[1];
            const float a2 = w0_ * (float)v0[2] + w1_ * (float)v1[2] + w2_ * (float)v2[2] + w3_ * (float)v3[2];
            const float a3 = w0_ * (float)v0[3] + w1_ * (float)v1[3] + w2_ * (float)v2[3] + w3_ * (float)v3[3];

            __builtin_nontemporal_store(a0 + r0, out + gi);
            __builtin_nontemporal_store(a1 + r1, out + gi + (size_t)HWdim);
            __builtin_nontemporal_store(a2 + r2, out + gi + (size_t)(2 * HWdim));
            __builtin_nontemporal_store(a3 + r3, out + gi + (size_t)(3 * HWdim));
        }
    }
}

// ---------------------------------------------------------------------------
// Fallback (R1 kernel) if workspace is too small for the NHWC fp16 buffer
// ---------------------------------------------------------------------------
__global__ __launch_bounds__(256) void warp_add_kernel(
    const float* __restrict__ x,
    const float* __restrict__ flow,
    const float* __restrict__ residual,
    float* __restrict__ out)
{
    int tid = blockIdx.x * blockDim.x + threadIdx.x;
    int w = tid & (Wdim - 1);
    int h = (tid >> 9) & (Hdim - 1);
    int b = tid >> 18;

    const float fx = flow[((size_t)b * 2 + 0) * HWdim + h * Wdim + w];
    const float fy = flow[((size_t)b * 2 + 1) * HWdim + h * Wdim + w];

    float gx = ((float)w + 0.5f) * (2.0f / (float)Wdim) - 1.0f + fx;
    float gy = ((float)h + 0.5f) * (2.0f / (float)Hdim) - 1.0f + fy;
    {
        float t2 = fmodf(gx + 1.0f, 2.0f);
        if (t2 < 0.0f) t2 += 2.0f;
        gx = t2 - 1.0f;
    }
    const float real_x = (gx + 1.0f) * ((float)Wdim * 0.5f) - 0.5f;
    const float real_y = (gy + 1.0f) * ((float)Hdim * 0.5f) - 0.5f;
    const float x0f = floorf(real_x);
    const float y0f = floorf(real_y);
    const float dx = real_x - x0f;
    const float dy = real_y - y0f;
    const int ix0 = (int)x0f, iy0 = (int)y0f;
    const int ix1 = ix0 + 1,  iy1 = iy0 + 1;
    const bool vx0 = (ix0 >= 0) && (ix0 < Wdim);
    const bool vx1 = (ix1 >= 0) && (ix1 < Wdim);
    const bool vy0 = (iy0 >= 0) && (iy0 < Hdim);
    const bool vy1 = (iy1 >= 0) && (iy1 < Hdim);
    const int cx0 = min(max(ix0, 0), Wdim - 1);
    const int cx1 = min(max(ix1, 0), Wdim - 1);
    const int cy0 = min(max(iy0, 0), Hdim - 1);
    const int cy1 = min(max(iy1, 0), Hdim - 1);
    float w_tl = (1.0f - dx) * (1.0f - dy);
    float w_tr = dx * (1.0f - dy);
    float w_bl = (1.0f - dx) * dy;
    float w_br = dx * dy;
    if (!(vx0 && vy0)) w_tl = 0.0f;
    if (!(vx1 && vy0)) w_tr = 0.0f;
    if (!(vx0 && vy1)) w_bl = 0.0f;
    if (!(vx1 && vy1)) w_br = 0.0f;
    const int off_tl = cy0 * Wdim + cx0;
    const int off_tr = cy0 * Wdim + cx1;
    const int off_bl = cy1 * Wdim + cx0;
    const int off_br = cy1 * Wdim + cx1;
    const size_t base = (size_t)b * Cdim * HWdim;
    const int    pix  = h * Wdim + w;
    const float* xb = x + base;
    const float* rbp = residual + base + pix;
    float*       ob = out + base + pix;
    #pragma unroll 8
    for (int c = 0; c < Cdim; ++c) {
        const float* xc = xb + (size_t)c * HWdim;
        float v = w_tl * xc[off_tl] + w_tr * xc[off_tr]
                + w_bl * xc[off_bl] + w_br * xc[off_br]
                + rbp[(size_t)c * HWdim];
        ob[(size_t)c * HWdim] = v;
    }
}

extern "C" void kernel_launch(void* const* d_in, const int* in_sizes, int n_in,
                              void* d_out, int out_size, void* d_ws, size_t ws_size,
                              hipStream_t stream) {
    const float* x        = (const float*)d_in[0];
    const float* flow     = (const float*)d_in[1];
    const float* residual = (const float*)d_in[2];
    float* out            = (float*)d_out;

    const size_t ws_needed = (size_t)Bdim * Cdim * HWdim * sizeof(_Float16); // 64 MiB

    if (ws_size >= ws_needed) {
        _Float16* ws = (_Float16*)d_ws;
        transpose_nhwc_half_kernel<<<Bdim * Hdim * (Wdim / 128), 256, 0, stream>>>(x, ws);
        gather_nhwc_half_kernel<<<Bdim * Hdim * Wdim / 256, 256, 0, stream>>>(ws, flow, residual, out);
    } else {
        const int total = Bdim * Hdim * Wdim;
        warp_add_kernel<<<total / 256, 256, 0, stream>>>(x, flow, residual, out);
    }
}

// Round 3
// 354.684 us; speedup vs baseline: 1.3802x; 1.3802x over previous
//
#include <hip/hip_runtime.h>

// Problem constants (match reference)
#define Bdim 4
#define Cdim 32
#define Hdim 512
#define Wdim 512
#define HWdim (Hdim * Wdim)

typedef __attribute__((ext_vector_type(4))) float    f32x4;
typedef __attribute__((ext_vector_type(2))) _Float16 f16x2;
typedef __attribute__((ext_vector_type(4))) _Float16 f16x4;
typedef __attribute__((ext_vector_type(8))) _Float16 f16x8;

// ---------------------------------------------------------------------------
// Kernel A: transpose x [B][C][H][W] (fp32) -> ws NHWC [B][H][W][C] (fp16)
// One block: (b, h) fixed, 128-wide w strip, all 32 c.
// float4 global loads, f32x4 LDS stores (pad 132 -> 16B-aligned, conflict-free),
// f16x8 (16B) NHWC stores, 2 per thread (32B contiguous each).
// ---------------------------------------------------------------------------
__global__ __launch_bounds__(256) void transpose_nhwc_half_kernel(
    const float* __restrict__ x, _Float16* __restrict__ ws)
{
    __shared__ float lds[Cdim * 132];   // 32 x 132 floats = 16896 B

    const int idx = blockIdx.x;               // B*H*4 = 8192 blocks
    const int tw  = idx & 3;                  // W/128 = 4 strips
    const int h   = (idx >> 2) & (Hdim - 1);
    const int b   = idx >> 11;
    const int w0  = tw * 128;
    const int t   = threadIdx.x;

    // 32c x 128w = 1024 float4s, 4 per thread. Issue all loads first (MLP).
    f32x4 r[4];
    #pragma unroll
    for (int i = 0; i < 4; ++i) {
        const int f4 = i * 256 + t;           // 0..1023
        const int c  = f4 >> 5;               // 32 float4 per row
        const int w4 = f4 & 31;
        r[i] = *(const f32x4*)(x + (((size_t)b * Cdim + c) * Hdim + h) * Wdim + w0 + w4 * 4);
    }
    #pragma unroll
    for (int i = 0; i < 4; ++i) {
        const int f4 = i * 256 + t;
        *(f32x4*)(lds + (f4 >> 5) * 132 + (f4 & 31) * 4) = r[i];
    }
    __syncthreads();

    // output block = 4096 halves contiguous; thread t writes halves [t*16, t*16+16)
    const size_t base = (((size_t)b * Hdim + h) * Wdim + w0) * Cdim;
    const int w_ = t >> 1;                    // local w (0..127)
    const int c0 = (t & 1) * 16;              // first channel (0 or 16)
    f16x8 v0, v1;
    #pragma unroll
    for (int k = 0; k < 8; ++k) v0[k] = (_Float16)lds[(c0 + k) * 132 + w_];
    #pragma unroll
    for (int k = 0; k < 8; ++k) v1[k] = (_Float16)lds[(c0 + 8 + k) * 132 + w_];
    *(f16x8*)(ws + base + (size_t)w_ * Cdim + c0)     = v0;   // 16B store
    *(f16x8*)(ws + base + (size_t)w_ * Cdim + c0 + 8) = v1;   // 16B store
}

// ---------------------------------------------------------------------------
// Kernel B: gather from NHWC fp16 ws + residual -> out (NCHW fp32)
// Block = 256 consecutive pixels of one row (b, h, w0..w0+255).
// Round-0 structure (proven 83.9 us) with s_buf split into two 128-pixel
// halves to cut LDS 25.6 KB -> 16.9 KB (6 -> 8+ blocks/CU):
//   Phase 1: per-pixel flow math -> LDS offsets/weights (all 256 pixels)
//   Per half (128 pixels):
//     Phase 2: 8 lanes/pixel, 4 channels each; f16x4 corner loads
//              (8 lanes x 8B = full 64B NHWC line); fp32 weighted sum,
//              fp16 pack into s_buf (numerics identical to round-0).
//     Phase 3: 2 threads/pixel x 16 channels; s_buf read + residual add,
//              NT stores in >=128B contiguous runs per channel plane.
// ---------------------------------------------------------------------------
__global__ __launch_bounds__(256) void gather_nhwc_half_kernel(
    const _Float16* __restrict__ ws,
    const float* __restrict__ flow,
    const float* __restrict__ residual,
    float* __restrict__ out)
{
    __shared__ int      s_off[4][256];
    __shared__ float    s_wt[4][256];
    __shared__ _Float16 s_buf[128 * 34];   // [pix][c], stride 34 halves

    const int idx = blockIdx.x;                 // 4096 blocks
    const int b   = idx >> 10;
    const int h   = (idx >> 1) & (Hdim - 1);
    const int w0  = (idx & 1) << 8;
    const int t   = threadIdx.x;

    // ---- Phase 1: per-pixel sampling math (numerics identical to round-0) ----
    {
        const int w = w0 + t;
        const int pixg = h * Wdim + w;
        const float fx = flow[((size_t)b * 2 + 0) * HWdim + pixg];
        const float fy = flow[((size_t)b * 2 + 1) * HWdim + pixg];

        float gx = ((float)w + 0.5f) * (2.0f / (float)Wdim) - 1.0f + fx;
        float gy = ((float)h + 0.5f) * (2.0f / (float)Hdim) - 1.0f + fy;

        float tm = fmodf(gx + 1.0f, 2.0f);
        if (tm < 0.0f) tm += 2.0f;
        gx = tm - 1.0f;

        const float real_x = (gx + 1.0f) * ((float)Wdim * 0.5f) - 0.5f;
        const float real_y = (gy + 1.0f) * ((float)Hdim * 0.5f) - 0.5f;

        const float x0f = floorf(real_x);
        const float y0f = floorf(real_y);
        const float dx = real_x - x0f;
        const float dy = real_y - y0f;

        const int ix0 = (int)x0f;
        const int iy0 = (int)y0f;
        const int ix1 = ix0 + 1;
        const int iy1 = iy0 + 1;

        const bool vx0 = (ix0 >= 0) && (ix0 < Wdim);
        const bool vx1 = (ix1 >= 0) && (ix1 < Wdim);
        const bool vy0 = (iy0 >= 0) && (iy0 < Hdim);
        const bool vy1 = (iy1 >= 0) && (iy1 < Hdim);

        const int cx0 = min(max(ix0, 0), Wdim - 1);
        const int cx1 = min(max(ix1, 0), Wdim - 1);
        const int cy0 = min(max(iy0, 0), Hdim - 1);
        const int cy1 = min(max(iy1, 0), Hdim - 1);

        float w_tl = (1.0f - dx) * (1.0f - dy);
        float w_tr = dx * (1.0f - dy);
        float w_bl = (1.0f - dx) * dy;
        float w_br = dx * dy;
        if (!(vx0 && vy0)) w_tl = 0.0f;
        if (!(vx1 && vy0)) w_tr = 0.0f;
        if (!(vx0 && vy1)) w_bl = 0.0f;
        if (!(vx1 && vy1)) w_br = 0.0f;

        s_off[0][t] = (cy0 * Wdim + cx0) * Cdim;   // offsets in halves
        s_off[1][t] = (cy0 * Wdim + cx1) * Cdim;
        s_off[2][t] = (cy1 * Wdim + cx0) * Cdim;
        s_off[3][t] = (cy1 * Wdim + cx1) * Cdim;
        s_wt[0][t] = w_tl;
        s_wt[1][t] = w_tr;
        s_wt[2][t] = w_bl;
        s_wt[3][t] = w_br;
    }
    __syncthreads();

    const int ci = t & 7;          // channel quad: channels 4ci..4ci+3
    const int c0 = ci * 4;
    const int p  = t >> 3;         // 0..31 pixel slot
    const _Float16* xb = ws + (size_t)b * (size_t)HWdim * Cdim + c0;

    #pragma unroll
    for (int half = 0; half < 2; ++half) {
        // ---- Phase 2: coalesced channel-major gather into s_buf ----
        #pragma unroll 4
        for (int j = 0; j < 4; ++j) {
            const int lpix = j * 32 + p;            // 0..127 (s_buf slot)
            const int pix  = half * 128 + lpix;     // block-local pixel
            const int o0 = s_off[0][pix];
            const int o1 = s_off[1][pix];
            const int o2 = s_off[2][pix];
            const int o3 = s_off[3][pix];
            const float w0_ = s_wt[0][pix];
            const float w1_ = s_wt[1][pix];
            const float w2_ = s_wt[2][pix];
            const float w3_ = s_wt[3][pix];

            const f16x4 v0 = *(const f16x4*)(xb + o0);   // 8B load, 8 lanes = 64B line
            const f16x4 v1 = *(const f16x4*)(xb + o1);
            const f16x4 v2 = *(const f16x4*)(xb + o2);
            const f16x4 v3 = *(const f16x4*)(xb + o3);

            float a0 = w0_ * (float)v0[0] + w1_ * (float)v1[0] + w2_ * (float)v2[0] + w3_ * (float)v3[0];
            float a1 = w0_ * (float)v0[1] + w1_ * (float)v1[1] + w2_ * (float)v2[1] + w3_ * (float)v3[1];
            float a2 = w0_ * (float)v0[2] + w1_ * (float)v1[2] + w2_ * (float)v2[2] + w3_ * (float)v3[2];
            float a3 = w0_ * (float)v0[3] + w1_ * (float)v1[3] + w2_ * (float)v2[3] + w3_ * (float)v3[3];

            f16x2 h01; h01[0] = (_Float16)a0; h01[1] = (_Float16)a1;
            f16x2 h23; h23[0] = (_Float16)a2; h23[1] = (_Float16)a3;
            *(f16x2*)(s_buf + lpix * 34 + c0)     = h01;  // 4B LDS stores
            *(f16x2*)(s_buf + lpix * 34 + c0 + 2) = h23;
        }
        __syncthreads();

        // ---- Phase 3: coalesced NCHW store + residual (2 threads/pixel) ----
        {
            const int lpix = t >> 1;               // 0..127
            const int ch0  = (t & 1) * 16;         // channel half
            const size_t pbase = (size_t)h * Wdim + w0 + half * 128 + lpix;
            const _Float16* row = s_buf + lpix * 34 + ch0;
            #pragma unroll 8
            for (int cc = 0; cc < 16; cc += 2) {
                const f16x2 v = *(const f16x2*)(row + cc);
                const size_t gi0 = ((size_t)b * Cdim + ch0 + cc) * HWdim + pbase;
                const float r0 = __builtin_nontemporal_load(residual + gi0);
                const float r1 = __builtin_nontemporal_load(residual + gi0 + HWdim);
                __builtin_nontemporal_store((float)v[0] + r0, out + gi0);
                __builtin_nontemporal_store((float)v[1] + r1, out + gi0 + HWdim);
            }
        }
        if (half == 0) __syncthreads();   // protect s_buf reuse
    }
}

// ---------------------------------------------------------------------------
// Fallback (R1 kernel) if workspace is too small for the NHWC fp16 buffer
// ---------------------------------------------------------------------------
__global__ __launch_bounds__(256) void warp_add_kernel(
    const float* __restrict__ x,
    const float* __restrict__ flow,
    const float* __restrict__ residual,
    float* __restrict__ out)
{
    int tid = blockIdx.x * blockDim.x + threadIdx.x;
    int w = tid & (Wdim - 1);
    int h = (tid >> 9) & (Hdim - 1);
    int b = tid >> 18;

    const float fx = flow[((size_t)b * 2 + 0) * HWdim + h * Wdim + w];
    const float fy = flow[((size_t)b * 2 + 1) * HWdim + h * Wdim + w];

    float gx = ((float)w + 0.5f) * (2.0f / (float)Wdim) - 1.0f + fx;
    float gy = ((float)h + 0.5f) * (2.0f / (float)Hdim) - 1.0f + fy;
    {
        float t2 = fmodf(gx + 1.0f, 2.0f);
        if (t2 < 0.0f) t2 += 2.0f;
        gx = t2 - 1.0f;
    }
    const float real_x = (gx + 1.0f) * ((float)Wdim * 0.5f) - 0.5f;
    const float real_y = (gy + 1.0f) * ((float)Hdim * 0.5f) - 0.5f;
    const float x0f = floorf(real_x);
    const float y0f = floorf(real_y);
    const float dx = real_x - x0f;
    const float dy = real_y - y0f;
    const int ix0 = (int)x0f, iy0 = (int)y0f;
    const int ix1 = ix0 + 1,  iy1 = iy0 + 1;
    const bool vx0 = (ix0 >= 0) && (ix0 < Wdim);
    const bool vx1 = (ix1 >= 0) && (ix1 < Wdim);
    const bool vy0 = (iy0 >= 0) && (iy0 < Hdim);
    const bool vy1 = (iy1 >= 0) && (iy1 < Hdim);
    const int cx0 = min(max(ix0, 0), Wdim - 1);
    const int cx1 = min(max(ix1, 0), Wdim - 1);
    const int cy0 = min(max(iy0, 0), Hdim - 1);
    const int cy1 = min(max(iy1, 0), Hdim - 1);
    float w_tl = (1.0f - dx) * (1.0f - dy);
    float w_tr = dx * (1.0f - dy);
    float w_bl = (1.0f - dx) * dy;
    float w_br = dx * dy;
    if (!(vx0 && vy0)) w_tl = 0.0f;
    if (!(vx1 && vy0)) w_tr = 0.0f;
    if (!(vx0 && vy1)) w_bl = 0.0f;
    if (!(vx1 && vy1)) w_br = 0.0f;
    const int off_tl = cy0 * Wdim + cx0;
    const int off_tr = cy0 * Wdim + cx1;
    const int off_bl = cy1 * Wdim + cx0;
    const int off_br = cy1 * Wdim + cx1;
    const size_t base = (size_t)b * Cdim * HWdim;
    const int    pix  = h * Wdim + w;
    const float* xb = x + base;
    const float* rbp = residual + base + pix;
    float*       ob = out + base + pix;
    #pragma unroll 8
    for (int c = 0; c < Cdim; ++c) {
        const float* xc = xb + (size_t)c * HWdim;
        float v = w_tl * xc[off_tl] + w_tr * xc[off_tr]
                + w_bl * xc[off_bl] + w_br * xc[off_br]
                + rbp[(size_t)c * HWdim];
        ob[(size_t)c * HWdim] = v;
    }
}

extern "C" void kernel_launch(void* const* d_in, const int* in_sizes, int n_in,
                              void* d_out, int out_size, void* d_ws, size_t ws_size,
                              hipStream_t stream) {
    const float* x        = (const float*)d_in[0];
    const float* flow     = (const float*)d_in[1];
    const float* residual = (const float*)d_in[2];
    float* out            = (float*)d_out;

    const size_t ws_needed = (size_t)Bdim * Cdim * HWdim * sizeof(_Float16); // 64 MiB

    if (ws_size >= ws_needed) {
        _Float16* ws = (_Float16*)d_ws;
        transpose_nhwc_half_kernel<<<Bdim * Hdim * (Wdim / 128), 256, 0, stream>>>(x, ws);
        gather_nhwc_half_kernel<<<Bdim * Hdim * Wdim / 256, 256, 0, stream>>>(ws, flow, residual, out);
    } else {
        const int total = Bdim * Hdim * Wdim;
        warp_add_kernel<<<total / 256, 256, 0, stream>>>(x, flow, residual, out);
    }
}

// Round 4
// 344.076 us; speedup vs baseline: 1.4228x; 1.0308x over previous
//
#include <hip/hip_runtime.h>

// Problem constants (match reference)
#define Bdim 4
#define Cdim 32
#define Hdim 512
#define Wdim 512
#define HWdim (Hdim * Wdim)

typedef __attribute__((ext_vector_type(4))) float    f32x4;
typedef __attribute__((ext_vector_type(2))) _Float16 f16x2;
typedef __attribute__((ext_vector_type(4))) _Float16 f16x4;
typedef __attribute__((ext_vector_type(8))) _Float16 f16x8;

// ---------------------------------------------------------------------------
// Kernel A: transpose x [B][C][H][W] (fp32) -> ws NHWC [B][H][W][C] (fp16)
// One block: (b, h) fixed, 128-wide w strip, all 32 c.
// float4 global loads, f32x4 LDS stores (pad 132 -> 16B-aligned, conflict-free),
// f16x8 (16B) NHWC stores, 2 per thread (32B contiguous each).
// ---------------------------------------------------------------------------
__global__ __launch_bounds__(256) void transpose_nhwc_half_kernel(
    const float* __restrict__ x, _Float16* __restrict__ ws)
{
    __shared__ float lds[Cdim * 132];   // 32 x 132 floats = 16896 B

    const int idx = blockIdx.x;               // B*H*4 = 8192 blocks
    const int tw  = idx & 3;                  // W/128 = 4 strips
    const int h   = (idx >> 2) & (Hdim - 1);
    const int b   = idx >> 11;
    const int w0  = tw * 128;
    const int t   = threadIdx.x;

    // 32c x 128w = 1024 float4s, 4 per thread. Issue all loads first (MLP).
    f32x4 r[4];
    #pragma unroll
    for (int i = 0; i < 4; ++i) {
        const int f4 = i * 256 + t;           // 0..1023
        const int c  = f4 >> 5;               // 32 float4 per row
        const int w4 = f4 & 31;
        r[i] = *(const f32x4*)(x + (((size_t)b * Cdim + c) * Hdim + h) * Wdim + w0 + w4 * 4);
    }
    #pragma unroll
    for (int i = 0; i < 4; ++i) {
        const int f4 = i * 256 + t;
        *(f32x4*)(lds + (f4 >> 5) * 132 + (f4 & 31) * 4) = r[i];
    }
    __syncthreads();

    // output block = 4096 halves contiguous; thread t writes halves [t*16, t*16+16)
    const size_t base = (((size_t)b * Hdim + h) * Wdim + w0) * Cdim;
    const int w_ = t >> 1;                    // local w (0..127)
    const int c0 = (t & 1) * 16;              // first channel (0 or 16)
    f16x8 v0, v1;
    #pragma unroll
    for (int k = 0; k < 8; ++k) v0[k] = (_Float16)lds[(c0 + k) * 132 + w_];
    #pragma unroll
    for (int k = 0; k < 8; ++k) v1[k] = (_Float16)lds[(c0 + 8 + k) * 132 + w_];
    *(f16x8*)(ws + base + (size_t)w_ * Cdim + c0)     = v0;   // 16B store
    *(f16x8*)(ws + base + (size_t)w_ * Cdim + c0 + 8) = v1;   // 16B store
}

// ---------------------------------------------------------------------------
// Kernel B: gather from NHWC fp16 ws + residual -> out (NCHW fp32)
// Block = 256 consecutive pixels of one row; wave wv OWNS pixels
// [wv*64, wv*64+64) end-to-end -> ZERO __syncthreads.
//   Phase 1: per-lane flow math for its own pixel; results stay in REGISTERS.
//   Phase 2: 8 passes x 8 pixels/wave; lane = (pixel-slot, channel-quad).
//            Offsets/weights fetched via __shfl (ds_bpermute broadcast).
//            2-deep software pipeline: pass j+1's 4x f16x4 corner loads
//            (8 lanes x 8B = full 64B NHWC line) issued before consuming
//            pass j. fp32 weighted sum -> fp16 pack -> per-wave s_buf region.
//   Phase 3: wave-internal lgkmcnt wait (NO barrier); lane reads its own
//            pixel's 32 channels, adds NT residual, NT stores in 256B runs.
// XCD-chunked block swizzle: both w-halves of a row + adjacent rows land on
// the same XCD's L2 -> ws corner lines fetched into one L2, not 8.
// ---------------------------------------------------------------------------
__global__ __launch_bounds__(256) void gather_nhwc_half_kernel(
    const _Float16* __restrict__ ws,
    const float* __restrict__ flow,
    const float* __restrict__ residual,
    float* __restrict__ out)
{
    __shared__ _Float16 s_buf[4 * 64 * 34];   // 17408 B, 4 disjoint per-wave regions

    // bijective XCD-chunk swizzle (4096 blocks, 8 XCDs, 512 per chunk)
    const int orig = blockIdx.x;
    const int idx  = (orig & 7) * 512 + (orig >> 3);

    const int b    = idx >> 10;
    const int h    = (idx >> 1) & (Hdim - 1);
    const int w0   = (idx & 1) << 8;
    const int t    = threadIdx.x;
    const int lane = t & 63;
    const int wv   = t >> 6;

    // ---- Phase 1: per-pixel sampling math -> registers (numerics = R0) ----
    int   off0, off1, off2, off3;
    float wt0,  wt1,  wt2,  wt3;
    {
        const int w = w0 + t;
        const int pixg = h * Wdim + w;
        const float fx = flow[((size_t)b * 2 + 0) * HWdim + pixg];
        const float fy = flow[((size_t)b * 2 + 1) * HWdim + pixg];

        float gx = ((float)w + 0.5f) * (2.0f / (float)Wdim) - 1.0f + fx;
        float gy = ((float)h + 0.5f) * (2.0f / (float)Hdim) - 1.0f + fy;

        float tm = fmodf(gx + 1.0f, 2.0f);
        if (tm < 0.0f) tm += 2.0f;
        gx = tm - 1.0f;

        const float real_x = (gx + 1.0f) * ((float)Wdim * 0.5f) - 0.5f;
        const float real_y = (gy + 1.0f) * ((float)Hdim * 0.5f) - 0.5f;

        const float x0f = floorf(real_x);
        const float y0f = floorf(real_y);
        const float dx = real_x - x0f;
        const float dy = real_y - y0f;

        const int ix0 = (int)x0f;
        const int iy0 = (int)y0f;
        const int ix1 = ix0 + 1;
        const int iy1 = iy0 + 1;

        const bool vx0 = (ix0 >= 0) && (ix0 < Wdim);
        const bool vx1 = (ix1 >= 0) && (ix1 < Wdim);
        const bool vy0 = (iy0 >= 0) && (iy0 < Hdim);
        const bool vy1 = (iy1 >= 0) && (iy1 < Hdim);

        const int cx0 = min(max(ix0, 0), Wdim - 1);
        const int cx1 = min(max(ix1, 0), Wdim - 1);
        const int cy0 = min(max(iy0, 0), Hdim - 1);
        const int cy1 = min(max(iy1, 0), Hdim - 1);

        float w_tl = (1.0f - dx) * (1.0f - dy);
        float w_tr = dx * (1.0f - dy);
        float w_bl = (1.0f - dx) * dy;
        float w_br = dx * dy;
        if (!(vx0 && vy0)) w_tl = 0.0f;
        if (!(vx1 && vy0)) w_tr = 0.0f;
        if (!(vx0 && vy1)) w_bl = 0.0f;
        if (!(vx1 && vy1)) w_br = 0.0f;

        off0 = (cy0 * Wdim + cx0) * Cdim;   // offsets in halves
        off1 = (cy0 * Wdim + cx1) * Cdim;
        off2 = (cy1 * Wdim + cx0) * Cdim;
        off3 = (cy1 * Wdim + cx1) * Cdim;
        wt0 = w_tl; wt1 = w_tr; wt2 = w_bl; wt3 = w_br;
    }

    // ---- Phase 2: wave-local channel-major gather, 2-deep pipeline ----
    {
        const int ci = lane & 7;            // channel quad: channels 4ci..4ci+3
        const int c0 = ci * 4;
        const int ps = lane >> 3;           // pixel slot within pass (0..7)
        const _Float16* xb = ws + (size_t)b * (size_t)HWdim * Cdim + c0;
        _Float16* sb = s_buf + wv * (64 * 34);

        int   co[4]; float cw[4]; f16x4 cv[4];
        {
            const int sj = ps;              // pass 0: wave-relative src lane
            co[0] = __shfl(off0, sj, 64); co[1] = __shfl(off1, sj, 64);
            co[2] = __shfl(off2, sj, 64); co[3] = __shfl(off3, sj, 64);
            cw[0] = __shfl(wt0, sj, 64);  cw[1] = __shfl(wt1, sj, 64);
            cw[2] = __shfl(wt2, sj, 64);  cw[3] = __shfl(wt3, sj, 64);
            #pragma unroll
            for (int k = 0; k < 4; ++k) cv[k] = *(const f16x4*)(xb + co[k]);
        }

        #pragma unroll
        for (int j = 0; j < 8; ++j) {
            int   no[4]; float nw[4]; f16x4 nv[4];
            if (j < 7) {
                const int sj = (j + 1) * 8 + ps;
                no[0] = __shfl(off0, sj, 64); no[1] = __shfl(off1, sj, 64);
                no[2] = __shfl(off2, sj, 64); no[3] = __shfl(off3, sj, 64);
                nw[0] = __shfl(wt0, sj, 64);  nw[1] = __shfl(wt1, sj, 64);
                nw[2] = __shfl(wt2, sj, 64);  nw[3] = __shfl(wt3, sj, 64);
                #pragma unroll
                for (int k = 0; k < 4; ++k) nv[k] = *(const f16x4*)(xb + no[k]);
            }

            const int lpix = j * 8 + ps;    // 0..63 within wave region
            const float a0 = cw[0] * (float)cv[0][0] + cw[1] * (float)cv[1][0]
                           + cw[2] * (float)cv[2][0] + cw[3] * (float)cv[3][0];
            const float a1 = cw[0] * (float)cv[0][1] + cw[1] * (float)cv[1][1]
                           + cw[2] * (float)cv[2][1] + cw[3] * (float)cv[3][1];
            const float a2 = cw[0] * (float)cv[0][2] + cw[1] * (float)cv[1][2]
                           + cw[2] * (float)cv[2][2] + cw[3] * (float)cv[3][2];
            const float a3 = cw[0] * (float)cv[0][3] + cw[1] * (float)cv[1][3]
                           + cw[2] * (float)cv[2][3] + cw[3] * (float)cv[3][3];

            f16x2 h01; h01[0] = (_Float16)a0; h01[1] = (_Float16)a1;
            f16x2 h23; h23[0] = (_Float16)a2; h23[1] = (_Float16)a3;
            *(f16x2*)(sb + lpix * 34 + c0)     = h01;  // 4B LDS stores
            *(f16x2*)(sb + lpix * 34 + c0 + 2) = h23;

            if (j < 7) {
                #pragma unroll
                for (int k = 0; k < 4; ++k) { co[k] = no[k]; cw[k] = nw[k]; cv[k] = nv[k]; }
            }
        }
    }

    // wave-internal ordering: all DS writes visible before DS reads (no barrier)
    __builtin_amdgcn_wave_barrier();
    asm volatile("s_waitcnt lgkmcnt(0)" ::: "memory");
    __builtin_amdgcn_sched_barrier(0);

    // ---- Phase 3: lane owns its pixel; coalesced NCHW store + residual ----
    {
        const size_t pbase = (size_t)h * Wdim + w0 + t;
        const _Float16* row = s_buf + wv * (64 * 34) + lane * 34;
        #pragma unroll 8
        for (int cc = 0; cc < Cdim; cc += 2) {
            const f16x2 v = *(const f16x2*)(row + cc);
            const size_t gi0 = ((size_t)b * Cdim + cc) * HWdim + pbase;
            const float r0 = __builtin_nontemporal_load(residual + gi0);
            const float r1 = __builtin_nontemporal_load(residual + gi0 + HWdim);
            __builtin_nontemporal_store((float)v[0] + r0, out + gi0);
            __builtin_nontemporal_store((float)v[1] + r1, out + gi0 + HWdim);
        }
    }
}

// ---------------------------------------------------------------------------
// Fallback (R1 kernel) if workspace is too small for the NHWC fp16 buffer
// ---------------------------------------------------------------------------
__global__ __launch_bounds__(256) void warp_add_kernel(
    const float* __restrict__ x,
    const float* __restrict__ flow,
    const float* __restrict__ residual,
    float* __restrict__ out)
{
    int tid = blockIdx.x * blockDim.x + threadIdx.x;
    int w = tid & (Wdim - 1);
    int h = (tid >> 9) & (Hdim - 1);
    int b = tid >> 18;

    const float fx = flow[((size_t)b * 2 + 0) * HWdim + h * Wdim + w];
    const float fy = flow[((size_t)b * 2 + 1) * HWdim + h * Wdim + w];

    float gx = ((float)w + 0.5f) * (2.0f / (float)Wdim) - 1.0f + fx;
    float gy = ((float)h + 0.5f) * (2.0f / (float)Hdim) - 1.0f + fy;
    {
        float t2 = fmodf(gx + 1.0f, 2.0f);
        if (t2 < 0.0f) t2 += 2.0f;
        gx = t2 - 1.0f;
    }
    const float real_x = (gx + 1.0f) * ((float)Wdim * 0.5f) - 0.5f;
    const float real_y = (gy + 1.0f) * ((float)Hdim * 0.5f) - 0.5f;
    const float x0f = floorf(real_x);
    const float y0f = floorf(real_y);
    const float dx = real_x - x0f;
    const float dy = real_y - y0f;
    const int ix0 = (int)x0f, iy0 = (int)y0f;
    const int ix1 = ix0 + 1,  iy1 = iy0 + 1;
    const bool vx0 = (ix0 >= 0) && (ix0 < Wdim);
    const bool vx1 = (ix1 >= 0) && (ix1 < Wdim);
    const bool vy0 = (iy0 >= 0) && (iy0 < Hdim);
    const bool vy1 = (iy1 >= 0) && (iy1 < Hdim);
    const int cx0 = min(max(ix0, 0), Wdim - 1);
    const int cx1 = min(max(ix1, 0), Wdim - 1);
    const int cy0 = min(max(iy0, 0), Hdim - 1);
    const int cy1 = min(max(iy1, 0), Hdim - 1);
    float w_tl = (1.0f - dx) * (1.0f - dy);
    float w_tr = dx * (1.0f - dy);
    float w_bl = (1.0f - dx) * dy;
    float w_br = dx * dy;
    if (!(vx0 && vy0)) w_tl = 0.0f;
    if (!(vx1 && vy0)) w_tr = 0.0f;
    if (!(vx0 && vy1)) w_bl = 0.0f;
    if (!(vx1 && vy1)) w_br = 0.0f;
    const int off_tl = cy0 * Wdim + cx0;
    const int off_tr = cy0 * Wdim + cx1;
    const int off_bl = cy1 * Wdim + cx0;
    const int off_br = cy1 * Wdim + cx1;
    const size_t base = (size_t)b * Cdim * HWdim;
    const int    pix  = h * Wdim + w;
    const float* xb = x + base;
    const float* rbp = residual + base + pix;
    float*       ob = out + base + pix;
    #pragma unroll 8
    for (int c = 0; c < Cdim; ++c) {
        const float* xc = xb + (size_t)c * HWdim;
        float v = w_tl * xc[off_tl] + w_tr * xc[off_tr]
                + w_bl * xc[off_bl] + w_br * xc[off_br]
                + rbp[(size_t)c * HWdim];
        ob[(size_t)c * HWdim] = v;
    }
}

extern "C" void kernel_launch(void* const* d_in, const int* in_sizes, int n_in,
                              void* d_out, int out_size, void* d_ws, size_t ws_size,
                              hipStream_t stream) {
    const float* x        = (const float*)d_in[0];
    const float* flow     = (const float*)d_in[1];
    const float* residual = (const float*)d_in[2];
    float* out            = (float*)d_out;

    const size_t ws_needed = (size_t)Bdim * Cdim * HWdim * sizeof(_Float16); // 64 MiB

    if (ws_size >= ws_needed) {
        _Float16* ws = (_Float16*)d_ws;
        transpose_nhwc_half_kernel<<<Bdim * Hdim * (Wdim / 128), 256, 0, stream>>>(x, ws);
        gather_nhwc_half_kernel<<<Bdim * Hdim * Wdim / 256, 256, 0, stream>>>(ws, flow, residual, out);
    } else {
        const int total = Bdim * Hdim * Wdim;
        warp_add_kernel<<<total / 256, 256, 0, stream>>>(x, flow, residual, out);
    }
}